// Round 7
// baseline (859.905 us; speedup 1.0000x reference)
//
#include <hip/hip_runtime.h>

// MoE: x[8,4096,512]f32, assign[8,4096,2]i32, W1[8,512,2048], b1[8,2048],
//      W2[8,2048,512], b2[8,512] -> out[8,4096,512]f32
// v7: X-resident (staged+converted in-kernel, once); W1/W2 fragments loaded
//     DIRECTLY global->VGPR (no LDS staging, no ring, no per-phase barriers);
//     H double-buffered in LDS; ONE barrier per chunk. Expert==XCD affinity.

#define NTOK 32768
#define DIM  512
#define HID  2048
#define NE   8
#define TM   64
#define MAXTILE 128           // 128*64 = 8192 covers n_e (~7680+-80)

#define XBASE 0               // X: 64 rows x 1024B (64 units of 16B, swz low3)
#define HBASE 65536           // H: 2 x 32KB (64 rows x 512B, 32 units, swz low3)
#define LDS_BYTES 131072

typedef __attribute__((ext_vector_type(8))) short short8;
typedef __attribute__((ext_vector_type(4))) float f32x4;
typedef unsigned short ushort_t;

__device__ __forceinline__ unsigned short f2bf(float f) {
  union { float f; unsigned u; } v; v.f = f;
  unsigned r = v.u + 0x7FFFu + ((v.u >> 16) & 1u);  // RNE
  return (unsigned short)(r >> 16);
}

// ---------------- routing ----------------
__global__ void moe_route(const int* __restrict__ assign, int* __restrict__ cnt,
                          int* __restrict__ lists) {
  int t = blockIdx.x * blockDim.x + threadIdx.x;
  if (t >= NTOK) return;
  int a0 = assign[2 * t + 0];
  int a1 = assign[2 * t + 1];
  if (a0 == a1) {
    int p = atomicAdd(&cnt[a0], 1);
    lists[a0 * NTOK + p] = t | 0x10000;  // weight 1.0
  } else {
    int p0 = atomicAdd(&cnt[a0], 1);
    lists[a0 * NTOK + p0] = t;           // weight 0.5
    int p1 = atomicAdd(&cnt[a1], 1);
    lists[a1 * NTOK + p1] = t;
  }
}

// ---------------- weight transpose+convert ----------------
// src: [E][R][C] fp32 -> dst: [E][C][R] bf16
__global__ __launch_bounds__(256) void transp_cvt(const float* __restrict__ src,
                                                  ushort_t* __restrict__ dst,
                                                  int R, int C) {
  __shared__ float tile[64][68];
  const int e = blockIdx.z;
  const int rb = blockIdx.y * 64, cb = blockIdx.x * 64;
  const int t = threadIdx.x;
  {
    const int tr = t >> 2, tc = (t & 3) * 16;
    const f32x4* s = (const f32x4*)(src + ((size_t)e * R + rb + tr) * C + cb + tc);
    f32x4 v0 = __builtin_nontemporal_load(s + 0);
    f32x4 v1 = __builtin_nontemporal_load(s + 1);
    f32x4 v2 = __builtin_nontemporal_load(s + 2);
    f32x4 v3 = __builtin_nontemporal_load(s + 3);
    *(f32x4*)&tile[tr][tc + 0]  = v0;
    *(f32x4*)&tile[tr][tc + 4]  = v1;
    *(f32x4*)&tile[tr][tc + 8]  = v2;
    *(f32x4*)&tile[tr][tc + 12] = v3;
  }
  __syncthreads();
  {
    const int n = t >> 2, ks = (t & 3) * 16;
    short8 o0, o1;
#pragma unroll
    for (int j = 0; j < 8; ++j) o0[j] = (short)f2bf(tile[ks + j][n]);
#pragma unroll
    for (int j = 0; j < 8; ++j) o1[j] = (short)f2bf(tile[ks + 8 + j][n]);
    ushort_t* d = dst + ((size_t)e * C + cb + n) * R + rb + ks;
    *(short8*)(d) = o0;
    *(short8*)(d + 8) = o1;
  }
}

// ---------------- fused expert GEMM: X-resident, W direct-to-reg ----------------
__global__ __launch_bounds__(512, 1) void moe_gemm(
    const float* __restrict__ x, const ushort_t* __restrict__ W1b,
    const float* __restrict__ b1, const ushort_t* __restrict__ W2b,
    const float* __restrict__ b2, const int* __restrict__ cnt,
    const int* __restrict__ lists, float* __restrict__ out) {
  extern __shared__ char smem[];

  const int id = blockIdx.x;
  const int e = id & 7;          // expert == XCD (round-robin dispatch)
  const int tile = id >> 3;
  const int n_e = cnt[e];
  const int t0 = tile * TM;
  if (t0 >= n_e) return;

  const int tid = threadIdx.x;
  const int wid = tid >> 6;
  const int lane = tid & 63;
  const int lr = lane & 15, lg = lane >> 4;
  const int lr7 = lr & 7;

  // ---- stage X once: read x fp32 rows, convert, swizzled ds_write ----
  {
    int row = tid >> 3;
    int idx = t0 + row;
    int tok = lists[e * NTOK + (idx < n_e ? idx : 0)] & 0xFFFF;
    const float* xr = x + (size_t)tok * DIM;
#pragma unroll
    for (int i = 0; i < 8; ++i) {
      int u = (tid & 7) + 8 * i;
      f32x4 v0 = *(const f32x4*)(xr + u * 8);
      f32x4 v1 = *(const f32x4*)(xr + u * 8 + 4);
      short8 pk;
      pk[0] = (short)f2bf(v0.x); pk[1] = (short)f2bf(v0.y);
      pk[2] = (short)f2bf(v0.z); pk[3] = (short)f2bf(v0.w);
      pk[4] = (short)f2bf(v1.x); pk[5] = (short)f2bf(v1.y);
      pk[6] = (short)f2bf(v1.z); pk[7] = (short)f2bf(v1.w);
      int su = (u & ~7) | ((u & 7) ^ (row & 7));
      *(short8*)(smem + XBASE + row * 1024 + su * 16) = pk;
    }
  }
  __syncthreads();

  // per-lane W row bases (no LDS for W!)
  const ushort_t* gB1 = W1b + ((size_t)e * HID + wid * 32 + lr) * DIM;  // +nf*16*DIM
  const ushort_t* gB2 = W2b + ((size_t)e * DIM + wid * 64 + lr) * HID;  // +nf*16*HID

  f32x4 acc2[4][4];
#pragma unroll
  for (int i = 0; i < 4; ++i)
#pragma unroll
    for (int j = 0; j < 4; ++j) acc2[i][j] = f32x4{0.f, 0.f, 0.f, 0.f};

  for (int c = 0; c < 8; ++c) {
    char* Hbuf = smem + HBASE + (c & 1) * 32768;

    f32x4 acc1[4][2];
#pragma unroll
    for (int i = 0; i < 4; ++i) {
      acc1[i][0] = f32x4{0.f, 0.f, 0.f, 0.f};
      acc1[i][1] = f32x4{0.f, 0.f, 0.f, 0.f};
    }

    // ===== G1: acc1 = X[64x512] @ W1[:, c*256:+256]; no barriers =====
#pragma unroll
    for (int p = 0; p < 8; ++p) {
#pragma unroll
      for (int kf = 0; kf < 2; ++kf) {
        short8 av[4], bv[2];
#pragma unroll
        for (int nf = 0; nf < 2; ++nf)
          bv[nf] = *(const short8*)(gB1 + (size_t)(c * 256 + nf * 16) * DIM +
                                    p * 64 + kf * 32 + lg * 8);
#pragma unroll
        for (int mf = 0; mf < 4; ++mf) {
          int row = mf * 16 + lr;
          int u = p * 8 + kf * 4 + lg;
          av[mf] = *(const short8*)(smem + XBASE + row * 1024 +
                                    ((u & ~7) | ((u & 7) ^ (row & 7))) * 16);
        }
        __builtin_amdgcn_s_setprio(1);
#pragma unroll
        for (int mf = 0; mf < 4; ++mf)
#pragma unroll
          for (int nf = 0; nf < 2; ++nf)
            acc1[mf][nf] = __builtin_amdgcn_mfma_f32_16x16x32_bf16(
                av[mf], bv[nf], acc1[mf][nf], 0, 0, 0);
        __builtin_amdgcn_s_setprio(0);
      }
    }

    // ---- bias + relu -> Hbuf (swizzled bf16 [64 tok][256 hid]) ----
    {
      float b1v0 = b1[e * HID + c * 256 + wid * 32 + lr];
      float b1v1 = b1[e * HID + c * 256 + wid * 32 + 16 + lr];
#pragma unroll
      for (int mf = 0; mf < 4; ++mf)
#pragma unroll
        for (int nf = 0; nf < 2; ++nf)
#pragma unroll
          for (int r = 0; r < 4; ++r) {
            int wrow = mf * 16 + lg * 4 + r;
            int col = wid * 32 + nf * 16 + lr;
            float hv = fmaxf(acc1[mf][nf][r] + (nf ? b1v1 : b1v0), 0.0f);
            int u = col >> 3;
            *(ushort_t*)(Hbuf + wrow * 512 +
                         ((u & ~7) | ((u & 7) ^ (wrow & 7))) * 16 +
                         (col & 7) * 2) = f2bf(hv);
          }
    }
    asm volatile("s_waitcnt lgkmcnt(0)" ::: "memory");
    __builtin_amdgcn_s_barrier();

    // ===== G2: acc2 += H[64x256] @ W2[c*256:+256, :]; no barriers =====
#pragma unroll
    for (int kp = 0; kp < 4; ++kp) {
#pragma unroll
      for (int kf = 0; kf < 2; ++kf) {
        short8 a2[4], bw[4];
#pragma unroll
        for (int nf = 0; nf < 4; ++nf)
          bw[nf] = *(const short8*)(gB2 + (size_t)(nf * 16) * HID +
                                    c * 256 + kp * 64 + kf * 32 + lg * 8);
#pragma unroll
        for (int mf = 0; mf < 4; ++mf) {
          int row = mf * 16 + lr;
          int u = kp * 8 + kf * 4 + lg;
          a2[mf] = *(const short8*)(Hbuf + row * 512 +
                                    ((u & ~7) | ((u & 7) ^ (row & 7))) * 16);
        }
        __builtin_amdgcn_s_setprio(1);
#pragma unroll
        for (int mf = 0; mf < 4; ++mf)
#pragma unroll
          for (int nf = 0; nf < 4; ++nf)
            acc2[mf][nf] = __builtin_amdgcn_mfma_f32_16x16x32_bf16(
                a2[mf], bw[nf], acc2[mf][nf], 0, 0, 0);
        __builtin_amdgcn_s_setprio(0);
      }
    }
    // no trailing barrier: next G1 writes the OTHER H buffer; the lgkmcnt(0)
    // before the next chunk's barrier drains this wave's G2 reads first.
  }

  // ---- epilogue: out[tok] += (acc2 + b2) * w ----
  float b2v[4];
#pragma unroll
  for (int nf = 0; nf < 4; ++nf)
    b2v[nf] = b2[e * DIM + wid * 64 + nf * 16 + lr];

#pragma unroll
  for (int mf = 0; mf < 4; ++mf)
#pragma unroll
    for (int r = 0; r < 4; ++r) {
      int m = mf * 16 + lg * 4 + r;
      int gi = t0 + m;
      if (gi >= n_e) continue;
      int ent = lists[e * NTOK + gi];
      int t = ent & 0xFFFF;
      float w = (ent & 0x10000) ? 1.0f : 0.5f;
      float* orow = out + (size_t)t * DIM;
#pragma unroll
      for (int nf = 0; nf < 4; ++nf) {
        int col = wid * 64 + nf * 16 + lr;
        atomicAdd(orow + col, (acc2[mf][nf][r] + b2v[nf]) * w);
      }
    }
}

extern "C" void kernel_launch(void* const* d_in, const int* in_sizes, int n_in,
                              void* d_out, int out_size, void* d_ws, size_t ws_size,
                              hipStream_t stream) {
  const float* x      = (const float*)d_in[0];
  const int*   assign = (const int*)d_in[1];
  const float* W1     = (const float*)d_in[2];
  const float* b1     = (const float*)d_in[3];
  const float* W2     = (const float*)d_in[4];
  const float* b2     = (const float*)d_in[5];
  float* out = (float*)d_out;

  char* ws = (char*)d_ws;
  int* cnt   = (int*)ws;
  int* lists = (int*)(ws + 1024);
  ushort_t* W1b = (ushort_t*)(ws + (2ull << 20));              // 16.8 MB
  ushort_t* W2b = (ushort_t*)(ws + (2ull << 20) + 18874368ull); // 16.8 MB

  (void)hipMemsetAsync(d_out, 0, (size_t)out_size * sizeof(float), stream);
  (void)hipMemsetAsync(cnt, 0, 256, stream);

  moe_route<<<NTOK / 256, 256, 0, stream>>>(assign, cnt, lists);
  transp_cvt<<<dim3(HID / 64, DIM / 64, NE), 256, 0, stream>>>(W1, W1b, DIM, HID);
  transp_cvt<<<dim3(DIM / 64, HID / 64, NE), 256, 0, stream>>>(W2, W2b, HID, DIM);

  (void)hipFuncSetAttribute((const void*)moe_gemm,
                            hipFuncAttributeMaxDynamicSharedMemorySize, LDS_BYTES);
  moe_gemm<<<NE * MAXTILE, 512, LDS_BYTES, stream>>>(x, W1b, b1, W2b, b2,
                                                     cnt, lists, out);
}

// Round 8
// 825.701 us; speedup vs baseline: 1.0414x; 1.0414x over previous
//
#include <hip/hip_runtime.h>

// MoE: x[8,4096,512]f32, assign[8,4096,2]i32, W1[8,512,2048], b1[8,2048],
//      W2[8,2048,512], b2[8,512] -> out[8,4096,512]f32
// v8: X-resident TM=64; W1/W2 global->VGPR with EXPLICIT depth-3 register
//     pipeline (4-slot rotating wbuf, fully unrolled => static indices);
//     single H buffer; 2 raw barriers/chunk; merged prep kernel; NT X loads.

#define NTOK 32768
#define DIM  512
#define HID  2048
#define NE   8
#define TM   64
#define MAXTILE 128           // 128*64 = 8192 covers n_e (~7680+-80)

#define XBASE 0               // X: 64 rows x 1024B (64 16B-units, swz low3)
#define HBASE 65536           // H: 64 rows x 512B (32 16B-units, swz low3)
#define LDS_BYTES 98304

typedef __attribute__((ext_vector_type(8))) short short8;
typedef __attribute__((ext_vector_type(4))) float f32x4;
typedef unsigned short ushort_t;

__device__ __forceinline__ unsigned short f2bf(float f) {
  union { float f; unsigned u; } v; v.f = f;
  unsigned r = v.u + 0x7FFFu + ((v.u >> 16) & 1u);  // RNE
  return (unsigned short)(r >> 16);
}

// ---------------- merged prep: W transposes + routing ----------------
__device__ __forceinline__ void transp_body(const float* __restrict__ src,
                                            ushort_t* __restrict__ dst,
                                            int R, int C, int rb, int cb,
                                            int t, float tile[64][68]) {
  {
    const int tr = t >> 2, tc = (t & 3) * 16;
    const f32x4* s = (const f32x4*)(src + (size_t)(rb + tr) * C + cb + tc);
    f32x4 v0 = __builtin_nontemporal_load(s + 0);
    f32x4 v1 = __builtin_nontemporal_load(s + 1);
    f32x4 v2 = __builtin_nontemporal_load(s + 2);
    f32x4 v3 = __builtin_nontemporal_load(s + 3);
    *(f32x4*)&tile[tr][tc + 0]  = v0;
    *(f32x4*)&tile[tr][tc + 4]  = v1;
    *(f32x4*)&tile[tr][tc + 8]  = v2;
    *(f32x4*)&tile[tr][tc + 12] = v3;
  }
  __syncthreads();
  {
    const int n = t >> 2, ks = (t & 3) * 16;
    short8 o0, o1;
#pragma unroll
    for (int j = 0; j < 8; ++j) o0[j] = (short)f2bf(tile[ks + j][n]);
#pragma unroll
    for (int j = 0; j < 8; ++j) o1[j] = (short)f2bf(tile[ks + 8 + j][n]);
    ushort_t* d = dst + (size_t)(cb + n) * R + rb + ks;
    *(short8*)(d) = o0;
    *(short8*)(d + 8) = o1;
  }
}

__global__ __launch_bounds__(256) void moe_prep(
    const float* __restrict__ W1, const float* __restrict__ W2,
    ushort_t* __restrict__ W1b, ushort_t* __restrict__ W2b,
    const int* __restrict__ assign, int* __restrict__ cnt,
    int* __restrict__ lists) {
  __shared__ float tile[64][68];
  const int b = blockIdx.x;
  const int t = threadIdx.x;
  if (b < 2048) {                       // W1: [512][2048] -> [2048][512]
    int e = b >> 8, rem = b & 255;
    int rb = (rem >> 5) * 64, cb = (rem & 31) * 64;
    transp_body(W1 + (size_t)e * DIM * HID, W1b + (size_t)e * HID * DIM,
                DIM, HID, rb, cb, t, tile);
  } else if (b < 4096) {                // W2: [2048][512] -> [512][2048]
    int bb = b - 2048;
    int e = bb >> 8, rem = bb & 255;
    int rb = (rem >> 3) * 64, cb = (rem & 7) * 64;
    transp_body(W2 + (size_t)e * HID * DIM, W2b + (size_t)e * DIM * HID,
                HID, DIM, rb, cb, t, tile);
  } else {                              // routing
    int tt = (b - 4096) * 256 + t;
    int a0 = assign[2 * tt + 0];
    int a1 = assign[2 * tt + 1];
    if (a0 == a1) {
      int p = atomicAdd(&cnt[a0], 1);
      lists[a0 * NTOK + p] = tt | 0x10000;  // weight 1.0
    } else {
      int p0 = atomicAdd(&cnt[a0], 1);
      lists[a0 * NTOK + p0] = tt;           // weight 0.5
      int p1 = atomicAdd(&cnt[a1], 1);
      lists[a1 * NTOK + p1] = tt;
    }
  }
}

// ---------------- fused expert GEMM: X-resident, W reg-pipelined ----------------
__global__ __launch_bounds__(512, 2) void moe_gemm(
    const float* __restrict__ x, const ushort_t* __restrict__ W1b,
    const float* __restrict__ b1, const ushort_t* __restrict__ W2b,
    const float* __restrict__ b2, const int* __restrict__ cnt,
    const int* __restrict__ lists, float* __restrict__ out) {
  extern __shared__ char smem[];

  const int id = blockIdx.x;
  const int e = id & 7;          // expert == XCD (round-robin dispatch)
  const int tile = id >> 3;
  const int n_e = cnt[e];
  const int t0 = tile * TM;
  if (t0 >= n_e) return;

  const int tid = threadIdx.x;
  const int wid = tid >> 6;
  const int lane = tid & 63;
  const int lr = lane & 15, lg = lane >> 4;

  // per-lane W row bases
  const ushort_t* gW1 = W1b + ((size_t)e * HID + wid * 32 + lr) * DIM + lg * 8;
  const ushort_t* gW2 = W2b + ((size_t)e * DIM + wid * 64 + lr) * HID + lg * 8;

  // W register pipeline: 4 rotating slots, all indices compile-time static.
  short8 wbuf[4][4];
  auto issueW = [&](int cc, int s) {   // s: 0..15 -> G1 piece, 16..23 -> G2 piece
    short8* dst = wbuf[s & 3];
    if (s < 16) {
#pragma unroll
      for (int nf = 0; nf < 2; ++nf)
        dst[nf] = *(const short8*)(gW1 + (size_t)(cc * 256 + nf * 16) * DIM + s * 32);
    } else {
#pragma unroll
      for (int nf = 0; nf < 4; ++nf)
        dst[nf] = *(const short8*)(gW2 + (size_t)(nf * 16) * HID + cc * 256 + (s - 16) * 32);
    }
  };

  // ---- stage X once: fp32 -> bf16, swizzled ds_write (NT loads: keep W in L2) ----
  {
    int row = tid >> 3;
    int idx = t0 + row;
    int tok = lists[e * NTOK + (idx < n_e ? idx : 0)] & 0xFFFF;
    const float* xr = x + (size_t)tok * DIM;
#pragma unroll
    for (int i = 0; i < 8; ++i) {
      int u = (tid & 7) + 8 * i;
      f32x4 v0 = __builtin_nontemporal_load((const f32x4*)(xr + u * 8));
      f32x4 v1 = __builtin_nontemporal_load((const f32x4*)(xr + u * 8 + 4));
      short8 pk;
      pk[0] = (short)f2bf(v0.x); pk[1] = (short)f2bf(v0.y);
      pk[2] = (short)f2bf(v0.z); pk[3] = (short)f2bf(v0.w);
      pk[4] = (short)f2bf(v1.x); pk[5] = (short)f2bf(v1.y);
      pk[6] = (short)f2bf(v1.z); pk[7] = (short)f2bf(v1.w);
      int su = (u & ~7) | ((u & 7) ^ (row & 7));
      *(short8*)(smem + XBASE + row * 1024 + su * 16) = pk;
    }
  }
  // pipeline prologue (independent of LDS)
  issueW(0, 0); issueW(0, 1); issueW(0, 2);
  asm volatile("s_waitcnt lgkmcnt(0)" ::: "memory");
  __builtin_amdgcn_s_barrier();

  f32x4 acc2[4][4];
#pragma unroll
  for (int i = 0; i < 4; ++i)
#pragma unroll
    for (int j = 0; j < 4; ++j) acc2[i][j] = f32x4{0.f, 0.f, 0.f, 0.f};

  for (int c = 0; c < 8; ++c) {
    const int cn = (c + 1) & 7;

    float b1v0 = b1[e * HID + c * 256 + wid * 32 + lr];
    float b1v1 = b1[e * HID + c * 256 + wid * 32 + 16 + lr];

    f32x4 acc1[4][2];
#pragma unroll
    for (int i = 0; i < 4; ++i) {
      acc1[i][0] = f32x4{0.f, 0.f, 0.f, 0.f};
      acc1[i][1] = f32x4{0.f, 0.f, 0.f, 0.f};
    }

    // ===== G1: acc1 = X[64x512] @ W1[:, c*256:+256]; 16 sub-phases =====
#pragma unroll
    for (int s = 0; s < 16; ++s) {
      issueW(c, s + 3);                         // 3..18 (16..18 = G2 of same c)
      short8 av[4];
#pragma unroll
      for (int mf = 0; mf < 4; ++mf) {
        int row = mf * 16 + lr;
        int u = s * 4 + lg;
        av[mf] = *(const short8*)(smem + XBASE + row * 1024 +
                                  ((u & ~7) | ((u & 7) ^ (row & 7))) * 16);
      }
      __builtin_amdgcn_s_setprio(1);
#pragma unroll
      for (int mf = 0; mf < 4; ++mf)
#pragma unroll
        for (int nf = 0; nf < 2; ++nf)
          acc1[mf][nf] = __builtin_amdgcn_mfma_f32_16x16x32_bf16(
              av[mf], wbuf[s & 3][nf], acc1[mf][nf], 0, 0, 0);
      __builtin_amdgcn_s_setprio(0);
    }

    // ---- bias + relu -> H (swizzled bf16 [64 tok][256 hid]) ----
#pragma unroll
    for (int mf = 0; mf < 4; ++mf)
#pragma unroll
      for (int nf = 0; nf < 2; ++nf)
#pragma unroll
        for (int r = 0; r < 4; ++r) {
          int wrow = mf * 16 + lg * 4 + r;
          int col = wid * 32 + nf * 16 + lr;
          float hv = fmaxf(acc1[mf][nf][r] + (nf ? b1v1 : b1v0), 0.0f);
          int u = col >> 3;
          *(ushort_t*)(smem + HBASE + wrow * 512 +
                       ((u & ~7) | ((u & 7) ^ (wrow & 7))) * 16 +
                       (col & 7) * 2) = f2bf(hv);
        }
    asm volatile("s_waitcnt lgkmcnt(0)" ::: "memory");
    __builtin_amdgcn_s_barrier();

    // ===== G2: acc2 += H[64x256] @ W2[c*256:+256, :]; 8 sub-phases =====
#pragma unroll
    for (int s = 16; s < 24; ++s) {
      if (s + 3 < 24) issueW(c, s + 3);
      else            issueW(cn, s + 3 - 24);   // next chunk's G1 pieces 0..2
      short8 a2[4];
#pragma unroll
      for (int mf = 0; mf < 4; ++mf) {
        int row = mf * 16 + lr;
        int u = (s - 16) * 4 + lg;
        a2[mf] = *(const short8*)(smem + HBASE + row * 512 +
                                  ((u & ~7) | ((u & 7) ^ (row & 7))) * 16);
      }
      __builtin_amdgcn_s_setprio(1);
#pragma unroll
      for (int mf = 0; mf < 4; ++mf)
#pragma unroll
        for (int nf = 0; nf < 4; ++nf)
          acc2[mf][nf] = __builtin_amdgcn_mfma_f32_16x16x32_bf16(
              a2[mf], wbuf[s & 3][nf], acc2[mf][nf], 0, 0, 0);
      __builtin_amdgcn_s_setprio(0);
    }
    asm volatile("s_waitcnt lgkmcnt(0)" ::: "memory");
    __builtin_amdgcn_s_barrier();
  }

  // ---- epilogue: out[tok] += (acc2 + b2) * w ----
  float b2v[4];
#pragma unroll
  for (int nf = 0; nf < 4; ++nf)
    b2v[nf] = b2[e * DIM + wid * 64 + nf * 16 + lr];

#pragma unroll
  for (int mf = 0; mf < 4; ++mf)
#pragma unroll
    for (int r = 0; r < 4; ++r) {
      int m = mf * 16 + lg * 4 + r;
      int gi = t0 + m;
      if (gi >= n_e) continue;
      int ent = lists[e * NTOK + gi];
      int t = ent & 0xFFFF;
      float w = (ent & 0x10000) ? 1.0f : 0.5f;
      float* orow = out + (size_t)t * DIM;
#pragma unroll
      for (int nf = 0; nf < 4; ++nf) {
        int col = wid * 64 + nf * 16 + lr;
        atomicAdd(orow + col, (acc2[mf][nf][r] + b2v[nf]) * w);
      }
    }
}

extern "C" void kernel_launch(void* const* d_in, const int* in_sizes, int n_in,
                              void* d_out, int out_size, void* d_ws, size_t ws_size,
                              hipStream_t stream) {
  const float* x      = (const float*)d_in[0];
  const int*   assign = (const int*)d_in[1];
  const float* W1     = (const float*)d_in[2];
  const float* b1     = (const float*)d_in[3];
  const float* W2     = (const float*)d_in[4];
  const float* b2     = (const float*)d_in[5];
  float* out = (float*)d_out;

  char* ws = (char*)d_ws;
  int* cnt   = (int*)ws;
  int* lists = (int*)(ws + 1024);
  ushort_t* W1b = (ushort_t*)(ws + (2ull << 20));               // 16.8 MB
  ushort_t* W2b = (ushort_t*)(ws + (2ull << 20) + 18874368ull); // 16.8 MB

  (void)hipMemsetAsync(d_out, 0, (size_t)out_size * sizeof(float), stream);
  (void)hipMemsetAsync(cnt, 0, 256, stream);

  moe_prep<<<4096 + NTOK / 256, 256, 0, stream>>>(W1, W2, W1b, W2b,
                                                  assign, cnt, lists);

  (void)hipFuncSetAttribute((const void*)moe_gemm,
                            hipFuncAttributeMaxDynamicSharedMemorySize, LDS_BYTES);
  moe_gemm<<<NE * MAXTILE, 512, LDS_BYTES, stream>>>(x, W1b, b1, W2b, b2,
                                                     cnt, lists, out);
}

// Round 9
// 404.688 us; speedup vs baseline: 2.1249x; 2.0403x over previous
//
#include <hip/hip_runtime.h>

// MoE: x[8,4096,512]f32, assign[8,4096,2]i32, W1[8,512,2048], b1[8,2048],
//      W2[8,2048,512], b2[8,512] -> out[8,4096,512]f32
// v9: X-resident TM=64; WAVE-PRIVATE 4KB W pieces via global_load_lds with
//     per-wave counted vmcnt(4) ring (2 slots/wave) -- NO barriers in the W
//     pipeline. Only syncs: 1 syncthreads after X-stage + 2 raw s_barrier per
//     chunk around the H handoff. Expert==XCD affinity. LDS-ranked routing.

#define NTOK 32768
#define DIM  512
#define HID  2048
#define NE   8
#define TM   64
#define MAXTILE 128            // 128*64 = 8192 covers n_e (~7680+-90)

#define XBASE 0                // X: 64 rows x 1024B (64 16B-units, swz low3)
#define RBASE 65536            // rings: 8 waves x 2 slots x 4096B
#define HBASE 131072           // H: 64 rows x 512B (32 16B-units, swz low3)
#define LDS_BYTES 163840

typedef __attribute__((ext_vector_type(8))) short short8;
typedef __attribute__((ext_vector_type(4))) float f32x4;
typedef unsigned short ushort_t;

__device__ __forceinline__ unsigned short f2bf(float f) {
  union { float f; unsigned u; } v; v.f = f;
  unsigned r = v.u + 0x7FFFu + ((v.u >> 16) & 1u);  // RNE
  return (unsigned short)(r >> 16);
}
__device__ __forceinline__ void g2l16(const void* g, void* l) {
  __builtin_amdgcn_global_load_lds(
      (const __attribute__((address_space(1))) void*)g,
      (__attribute__((address_space(3))) void*)l, 16, 0, 0);
}

// ---------------- prep: W transposes + LDS-ranked routing ----------------
__device__ __forceinline__ void transp_body(const float* __restrict__ src,
                                            ushort_t* __restrict__ dst,
                                            int R, int C, int rb, int cb,
                                            int t, float tile[64][68]) {
  {
    const int tr = t >> 2, tc = (t & 3) * 16;
    const f32x4* s = (const f32x4*)(src + (size_t)(rb + tr) * C + cb + tc);
    f32x4 v0 = __builtin_nontemporal_load(s + 0);
    f32x4 v1 = __builtin_nontemporal_load(s + 1);
    f32x4 v2 = __builtin_nontemporal_load(s + 2);
    f32x4 v3 = __builtin_nontemporal_load(s + 3);
    *(f32x4*)&tile[tr][tc + 0]  = v0;
    *(f32x4*)&tile[tr][tc + 4]  = v1;
    *(f32x4*)&tile[tr][tc + 8]  = v2;
    *(f32x4*)&tile[tr][tc + 12] = v3;
  }
  __syncthreads();
  {
    const int n = t >> 2, ks = (t & 3) * 16;
    short8 o0, o1;
#pragma unroll
    for (int j = 0; j < 8; ++j) o0[j] = (short)f2bf(tile[ks + j][n]);
#pragma unroll
    for (int j = 0; j < 8; ++j) o1[j] = (short)f2bf(tile[ks + 8 + j][n]);
    ushort_t* d = dst + (size_t)(cb + n) * R + rb + ks;
    *(short8*)(d) = o0;
    *(short8*)(d + 8) = o1;
  }
}

__global__ __launch_bounds__(256) void moe_prep(
    const float* __restrict__ W1, const float* __restrict__ W2,
    ushort_t* __restrict__ W1b, ushort_t* __restrict__ W2b,
    const int* __restrict__ assign, int* __restrict__ cnt,
    int* __restrict__ lists) {
  __shared__ float tile[64][68];
  __shared__ int lcnt[NE], gbase[NE];
  const int b = blockIdx.x;
  const int t = threadIdx.x;
  if (b < 2048) {                       // W1: [512][2048] -> [2048][512]
    int e = b >> 8, rem = b & 255;
    int rb = (rem >> 5) * 64, cb = (rem & 31) * 64;
    transp_body(W1 + (size_t)e * DIM * HID, W1b + (size_t)e * HID * DIM,
                DIM, HID, rb, cb, t, tile);
  } else if (b < 4096) {                // W2: [2048][512] -> [512][2048]
    int bb = b - 2048;
    int e = bb >> 8, rem = bb & 255;
    int rb = (rem >> 3) * 64, cb = (rem & 7) * 64;
    transp_body(W2 + (size_t)e * HID * DIM, W2b + (size_t)e * DIM * HID,
                HID, DIM, rb, cb, t, tile);
  } else {                              // routing: LDS histogram + rank
    int tt = (b - 4096) * 256 + t;
    if (t < NE) lcnt[t] = 0;
    __syncthreads();
    int a0 = assign[2 * tt + 0];
    int a1 = assign[2 * tt + 1];
    int r0, r1 = -1;
    r0 = atomicAdd(&lcnt[a0], 1);
    if (a0 != a1) r1 = atomicAdd(&lcnt[a1], 1);
    __syncthreads();
    if (t < NE) gbase[t] = atomicAdd(&cnt[t], lcnt[t]);
    __syncthreads();
    if (a0 == a1) {
      lists[a0 * NTOK + gbase[a0] + r0] = tt | 0x10000;   // weight 1.0
    } else {
      lists[a0 * NTOK + gbase[a0] + r0] = tt;             // weight 0.5
      lists[a1 * NTOK + gbase[a1] + r1] = tt;
    }
  }
}

// ---------- fused expert GEMM: X-resident, wave-private W rings ----------
__global__ __launch_bounds__(512, 2) void moe_gemm(
    const float* __restrict__ x, const ushort_t* __restrict__ W1b,
    const float* __restrict__ b1, const ushort_t* __restrict__ W2b,
    const float* __restrict__ b2, const int* __restrict__ cnt,
    const int* __restrict__ lists, float* __restrict__ out) {
  extern __shared__ char smem[];

  const int id = blockIdx.x;
  const int e = id & 7;          // expert == XCD (round-robin dispatch)
  const int tile = id >> 3;
  const int n_e = cnt[e];
  const int t0 = tile * TM;
  if (t0 >= n_e) return;

  const int tid = threadIdx.x;
  const int wid = tid >> 6;
  const int lane = tid & 63;
  const int lr = lane & 15, lg = lane >> 4;
  const int l3 = lane >> 3, l7 = lane & 7;

  char* const ring0 = smem + RBASE + wid * 8192;

  // wave-private piece staging (4 g2l16 each)
  auto stW1 = [&](int c, int p, int par) {     // 32 hid-rows x 64 k, swz src
    char* d = ring0 + par * 4096;
#pragma unroll
    for (int i = 0; i < 4; ++i) {
      const ushort_t* g = W1b +
          ((size_t)(e * HID + c * 256 + wid * 32 + i * 8 + l3)) * DIM +
          p * 64 + (l7 ^ l3) * 8;
      g2l16(g, d + i * 1024 + lane * 16);
    }
  };
  auto stW2 = [&](int c, int q, int par) {     // 64 out-rows x 32 k
    char* d = ring0 + par * 4096;
#pragma unroll
    for (int i = 0; i < 4; ++i) {
      const ushort_t* g = W2b +
          ((size_t)(e * DIM + wid * 64 + i * 16 + (lane >> 2))) * HID +
          c * 256 + q * 32 + (lane & 3) * 8;
      g2l16(g, d + i * 1024 + lane * 16);
    }
  };

  // ---- prologue: b1(c0), X-stage (fp32->bf16, NT), one syncthreads ----
  float b1c0 = b1[e * HID + wid * 32 + lr];
  float b1c1 = b1[e * HID + wid * 32 + 16 + lr];
  {
    int row = tid >> 3;
    int idx = t0 + row;
    int tok = lists[e * NTOK + (idx < n_e ? idx : 0)] & 0xFFFF;
    const float* xr = x + (size_t)tok * DIM;
#pragma unroll
    for (int i = 0; i < 8; ++i) {
      int u = (tid & 7) + 8 * i;
      f32x4 v0 = __builtin_nontemporal_load((const f32x4*)(xr + u * 8));
      f32x4 v1 = __builtin_nontemporal_load((const f32x4*)(xr + u * 8 + 4));
      short8 pk;
      pk[0] = (short)f2bf(v0.x); pk[1] = (short)f2bf(v0.y);
      pk[2] = (short)f2bf(v0.z); pk[3] = (short)f2bf(v0.w);
      pk[4] = (short)f2bf(v1.x); pk[5] = (short)f2bf(v1.y);
      pk[6] = (short)f2bf(v1.z); pk[7] = (short)f2bf(v1.w);
      int su = (u & ~7) | ((u & 7) ^ (row & 7));
      *(short8*)(smem + XBASE + row * 1024 + su * 16) = pk;
    }
  }
  __syncthreads();                 // drains everything; ring starts clean

  stW1(0, 0, 0);                   // piece 0

  f32x4 acc2[4][4];
#pragma unroll
  for (int i = 0; i < 4; ++i)
#pragma unroll
    for (int j = 0; j < 4; ++j) acc2[i][j] = f32x4{0.f, 0.f, 0.f, 0.f};

  for (int c = 0; c < 8; ++c) {
    const int cn = (c + 1) & 7;
    float b1n0 = 0.f, b1n1 = 0.f;

    f32x4 acc1[4][2];
#pragma unroll
    for (int i = 0; i < 4; ++i) {
      acc1[i][0] = f32x4{0.f, 0.f, 0.f, 0.f};
      acc1[i][1] = f32x4{0.f, 0.f, 0.f, 0.f};
    }

    // ===== G1: 8 phases (k64); wave-private ring, no barriers =====
#pragma unroll
    for (int p = 0; p < 8; ++p) {
      if (p < 7) stW1(c, p + 1, (p + 1) & 1);
      else       stW2(c, 0, 0);
      __builtin_amdgcn_sched_barrier(0);
      asm volatile("s_waitcnt vmcnt(4)" ::: "memory");
      __builtin_amdgcn_sched_barrier(0);

      const char* bp = ring0 + (p & 1) * 4096;
#pragma unroll
      for (int kf = 0; kf < 2; ++kf) {
        short8 av[4], bv[2];
#pragma unroll
        for (int mf = 0; mf < 4; ++mf) {
          int row = mf * 16 + lr;
          int u = p * 8 + kf * 4 + lg;
          av[mf] = *(const short8*)(smem + XBASE + row * 1024 +
                                    ((u & ~7) | ((u & 7) ^ (row & 7))) * 16);
        }
#pragma unroll
        for (int nf = 0; nf < 2; ++nf) {
          int row = nf * 16 + lr;                    // hid-local row
          bv[nf] = *(const short8*)(bp + row * 128 +
                                    (((kf * 4 + lg) ^ (row & 7))) * 16);
        }
        __builtin_amdgcn_s_setprio(1);
#pragma unroll
        for (int mf = 0; mf < 4; ++mf)
#pragma unroll
          for (int nf = 0; nf < 2; ++nf)
            acc1[mf][nf] = __builtin_amdgcn_mfma_f32_16x16x32_bf16(
                av[mf], bv[nf], acc1[mf][nf], 0, 0, 0);
        __builtin_amdgcn_s_setprio(0);
      }
    }

    // ===== H handoff: the ONLY block syncs (2 per chunk) =====
    asm volatile("s_waitcnt lgkmcnt(0)" ::: "memory");
    __builtin_amdgcn_s_barrier();            // everyone done reading H (G2 c-1)
#pragma unroll
    for (int mf = 0; mf < 4; ++mf)
#pragma unroll
      for (int nf = 0; nf < 2; ++nf)
#pragma unroll
        for (int r = 0; r < 4; ++r) {
          int m = mf * 16 + lg * 4 + r;
          int col = wid * 32 + nf * 16 + lr;
          float hv = fmaxf(acc1[mf][nf][r] + (nf ? b1c1 : b1c0), 0.0f);
          int u = col >> 3;
          *(ushort_t*)(smem + HBASE + m * 512 +
                       ((u & ~7) | ((u & 7) ^ (m & 7))) * 16 +
                       (col & 7) * 2) = f2bf(hv);
        }
    asm volatile("s_waitcnt lgkmcnt(0)" ::: "memory");
    __builtin_amdgcn_s_barrier();            // H visible to all

    // ===== G2: 8 phases (k32); wave-private ring, no barriers =====
#pragma unroll
    for (int q = 0; q < 8; ++q) {
      if (q == 0) {
        int bi = (c < 7) ? c + 1 : 7;
        b1n0 = b1[e * HID + bi * 256 + wid * 32 + lr];
        b1n1 = b1[e * HID + bi * 256 + wid * 32 + 16 + lr];
        __builtin_amdgcn_sched_barrier(0);
      }
      if (q < 7) stW2(c, q + 1, (q + 1) & 1);
      else       stW1(cn, 0, 0);
      __builtin_amdgcn_sched_barrier(0);
      if (q == 0) asm volatile("s_waitcnt vmcnt(6)" ::: "memory");
      else        asm volatile("s_waitcnt vmcnt(4)" ::: "memory");
      __builtin_amdgcn_sched_barrier(0);

      const char* bp = ring0 + (q & 1) * 4096;
      short8 a2[4], bw[4];
#pragma unroll
      for (int mf = 0; mf < 4; ++mf) {
        int row = mf * 16 + lr;
        int u = q * 4 + lg;
        a2[mf] = *(const short8*)(smem + HBASE + row * 512 +
                                  ((u & ~7) | ((u & 7) ^ (row & 7))) * 16);
      }
#pragma unroll
      for (int nf = 0; nf < 4; ++nf) {
        int row = nf * 16 + lr;                      // out-local row
        bw[nf] = *(const short8*)(bp + row * 64 + lg * 16);
      }
      __builtin_amdgcn_s_setprio(1);
#pragma unroll
      for (int mf = 0; mf < 4; ++mf)
#pragma unroll
        for (int nf = 0; nf < 4; ++nf)
          acc2[mf][nf] = __builtin_amdgcn_mfma_f32_16x16x32_bf16(
              a2[mf], bw[nf], acc2[mf][nf], 0, 0, 0);
      __builtin_amdgcn_s_setprio(0);
    }
    b1c0 = b1n0; b1c1 = b1n1;
  }
  asm volatile("" :: "v"(b1c0), "v"(b1c1));   // keep tail prefetch alive

  // ---- epilogue: out[tok] += (acc2 + b2) * w ----
  float b2v[4];
#pragma unroll
  for (int nf = 0; nf < 4; ++nf)
    b2v[nf] = b2[e * DIM + wid * 64 + nf * 16 + lr];

#pragma unroll
  for (int mf = 0; mf < 4; ++mf)
#pragma unroll
    for (int r = 0; r < 4; ++r) {
      int m = mf * 16 + lg * 4 + r;
      int gi = t0 + m;
      if (gi >= n_e) continue;
      int ent = lists[e * NTOK + gi];
      int t = ent & 0xFFFF;
      float w = (ent & 0x10000) ? 1.0f : 0.5f;
      float* orow = out + (size_t)t * DIM;
#pragma unroll
      for (int nf = 0; nf < 4; ++nf) {
        int col = wid * 64 + nf * 16 + lr;
        atomicAdd(orow + col, (acc2[mf][nf][r] + b2v[nf]) * w);
      }
    }
}

extern "C" void kernel_launch(void* const* d_in, const int* in_sizes, int n_in,
                              void* d_out, int out_size, void* d_ws, size_t ws_size,
                              hipStream_t stream) {
  const float* x      = (const float*)d_in[0];
  const int*   assign = (const int*)d_in[1];
  const float* W1     = (const float*)d_in[2];
  const float* b1     = (const float*)d_in[3];
  const float* W2     = (const float*)d_in[4];
  const float* b2     = (const float*)d_in[5];
  float* out = (float*)d_out;

  char* ws = (char*)d_ws;
  int* cnt   = (int*)ws;
  int* lists = (int*)(ws + 1024);
  ushort_t* W1b = (ushort_t*)(ws + (2ull << 20));               // 16.8 MB
  ushort_t* W2b = (ushort_t*)(ws + (2ull << 20) + 18874368ull); // 16.8 MB

  (void)hipMemsetAsync(d_out, 0, (size_t)out_size * sizeof(float), stream);
  (void)hipMemsetAsync(cnt, 0, 256, stream);

  moe_prep<<<4096 + NTOK / 256, 256, 0, stream>>>(W1, W2, W1b, W2b,
                                                  assign, cnt, lists);

  (void)hipFuncSetAttribute((const void*)moe_gemm,
                            hipFuncAttributeMaxDynamicSharedMemorySize, LDS_BYTES);
  moe_gemm<<<NE * MAXTILE, 512, LDS_BYTES, stream>>>(x, W1b, b1, W2b, b2,
                                                     cnt, lists, out);
}